// Round 1
// baseline (9799.078 us; speedup 1.0000x reference)
//
#include <hip/hip_runtime.h>
#include <hip/hip_bf16.h>

// ---------------- problem constants ----------------
#define BB 8192
#define TT 32
#define DD 12
#define ZZ 128
#define HE 512
#define HD 1024
#define KE 576    // 512 + 12 + pad -> multiple of 64
#define KD 1088   // 1024 + 12 + pad

typedef unsigned short u16;
typedef __attribute__((ext_vector_type(8))) short bf16x8;
typedef __attribute__((ext_vector_type(4))) float f32x4;

__device__ __forceinline__ u16 f2bf(float f) {
    __hip_bfloat16 h = __float2bfloat16(f);
    return *reinterpret_cast<u16*>(&h);
}
__device__ __forceinline__ float bf2f(u16 u) {
    __hip_bfloat16 h;
    *reinterpret_cast<u16*>(&h) = u;
    return __bfloat162float(h);
}
__device__ __forceinline__ float sigmf(float x) { return 1.f / (1.f + __expf(-x)); }
__device__ __forceinline__ float tanh_(float x) {
    float ax = fabsf(x);
    float e = __expf(-2.f * ax);
    float t = (1.f - e) / (1.f + e);
    return copysignf(t, x);
}

__device__ __forceinline__ void gload_lds16(const void* g, void* l) {
    __builtin_amdgcn_global_load_lds(
        (const __attribute__((address_space(1))) void*)g,
        (__attribute__((address_space(3))) void*)l,
        16, 0, 0);
}

// ---------------- GEMM: C[M][N] = A[M][K] * W[N][K]^T ----------------
// A, W row-major bf16 (K contiguous, K % 64 == 0), C fp32.
// 128x128 tile, BK=64, 4 waves (2x2), 16x16x32 bf16 MFMA. m97-class structure.
__global__ __launch_bounds__(256, 2)
void gemm_bt(const u16* __restrict__ A, const u16* __restrict__ W,
             float* __restrict__ C, int N, int K)
{
    __shared__ u16 As[128 * 64];
    __shared__ u16 Ws[128 * 64];
    const int tid  = threadIdx.x;
    const int lane = tid & 63;
    const int wave = tid >> 6;
    const int wm = wave >> 1, wn = wave & 1;
    const int bm = blockIdx.x * 128;
    const int bn = blockIdx.y * 128;

    f32x4 acc[4][4] = {};

    const int lrow = lane >> 3;        // 0..7
    const int lcol = (lane & 7) * 8;   // 0,8,..,56

    for (int kt = 0; kt < K; kt += 64) {
#pragma unroll
        for (int c2 = 0; c2 < 4; ++c2) {
            const int chunk = wave * 4 + c2;        // 0..15
            const int row = chunk * 8 + lrow;       // 0..127
            gload_lds16(A + (size_t)(bm + row) * K + kt + lcol, &As[chunk * 512]);
            gload_lds16(W + (size_t)(bn + row) * K + kt + lcol, &Ws[chunk * 512]);
        }
        __syncthreads();
#pragma unroll
        for (int ks = 0; ks < 2; ++ks) {
            bf16x8 af[4], wf[4];
            const int ko = ks * 32 + (lane >> 4) * 8;
            const int rA = wm * 64 + (lane & 15);
            const int rW = wn * 64 + (lane & 15);
#pragma unroll
            for (int i = 0; i < 4; ++i)
                af[i] = *(const bf16x8*)&As[(rA + i * 16) * 64 + ko];
#pragma unroll
            for (int i = 0; i < 4; ++i)
                wf[i] = *(const bf16x8*)&Ws[(rW + i * 16) * 64 + ko];
#pragma unroll
            for (int i = 0; i < 4; ++i)
#pragma unroll
                for (int j = 0; j < 4; ++j)
                    acc[i][j] = __builtin_amdgcn_mfma_f32_16x16x32_bf16(
                        af[i], wf[j], acc[i][j], 0, 0, 0);
        }
        __syncthreads();
    }

    // C/D layout: col = lane&15, row = (lane>>4)*4 + reg
    const int r0 = bm + wm * 64 + (lane >> 4) * 4;
    const int c0 = bn + wn * 64 + (lane & 15);
#pragma unroll
    for (int i = 0; i < 4; ++i)
#pragma unroll
        for (int j = 0; j < 4; ++j) {
            float* Cp = C + (size_t)(r0 + i * 16) * N + c0 + j * 16;
#pragma unroll
            for (int q = 0; q < 4; ++q)
                Cp[(size_t)q * N] = acc[i][j][q];
        }
}

// ---------------- weight concat: dst[n][k] = k<H ? Whh[n][k] : (k<H+12 ? Wih[n][k-H] : 0) ----
__global__ void prep_w(const float* __restrict__ Whh, const float* __restrict__ Wih,
                       u16* __restrict__ dst, int H, int Kc, int total)
{
    int idx = blockIdx.x * 256 + threadIdx.x;
    if (idx >= total) return;
    int n = idx / Kc, k = idx - n * Kc;
    float v = 0.f;
    if (k < H) v = Whh[(size_t)n * H + k];
    else if (k < H + DD) v = Wih[n * DD + (k - H)];
    dst[idx] = f2bf(v);
}

// ---------------- encoder init: h=0, c=0, x col = x[:,0,:], pad=0 ----------------
__global__ void init_enc(u16* __restrict__ A, float* __restrict__ c, const float* __restrict__ x)
{
    int idx = blockIdx.x * 256 + threadIdx.x;   // BB*KE
    int b = idx / KE, j = idx - b * KE;
    u16 v = 0;
    if (j >= HE && j < HE + DD) v = f2bf(x[(size_t)b * (TT * DD) + (j - HE)]);
    A[idx] = v;
    if (j < HE) c[(size_t)b * HE + j] = 0.f;
}

// ---------------- encoder LSTM pointwise ----------------
__global__ void ew_enc(const float* __restrict__ gates, const float* __restrict__ bias,
                       float* __restrict__ c, u16* __restrict__ A,
                       float* __restrict__ hn, const int* __restrict__ lens,
                       const float* __restrict__ x, int t)
{
    int idx = blockIdx.x * 256 + threadIdx.x;   // BB*HE
    int b = idx >> 9, j = idx & (HE - 1);
    const float* g = gates + ((size_t)b << 11);
    float iv = sigmf(g[j]            + bias[j]);
    float fv = sigmf(g[j + HE]       + bias[j + HE]);
    float gv = tanh_(g[j + 2 * HE]   + bias[j + 2 * HE]);
    float ov = sigmf(g[j + 3 * HE]   + bias[j + 3 * HE]);
    float cn = fv * c[idx] + iv * gv;
    float h  = ov * tanh_(cn);
    c[idx] = cn;
    A[(size_t)b * KE + j] = f2bf(h);
    int L = lens[b]; L = (L < 1) ? 1 : (L > TT ? TT : L);
    if (t == L - 1) hn[idx] = h;
    if (j < DD && t < TT - 1)
        A[(size_t)b * KE + HE + j] = f2bf(x[((size_t)b * TT + t + 1) * DD + j]);
}

// ---------------- mu / logvar / z ----------------
__global__ void muvz(const float* __restrict__ hn, const float* __restrict__ Wmu,
                     const float* __restrict__ bmu, const float* __restrict__ Wlv,
                     const float* __restrict__ blv, const float* __restrict__ eps,
                     float* __restrict__ out)
{
    int idx = blockIdx.x * 256 + threadIdx.x;   // BB*ZZ
    int b = idx >> 7, zc = idx & (ZZ - 1);
    const float* hr = hn + ((size_t)b << 9);
    const float* wm = Wmu + zc * HE;
    const float* wl = Wlv + zc * HE;
    float mu = bmu[zc], lv = blv[zc];
    for (int k = 0; k < HE; k += 4) {
        float4 hv = *(const float4*)&hr[k];
        float4 m4 = *(const float4*)&wm[k];
        float4 l4 = *(const float4*)&wl[k];
        mu += hv.x * m4.x + hv.y * m4.y + hv.z * m4.z + hv.w * m4.w;
        lv += hv.x * l4.x + hv.y * l4.y + hv.z * l4.z + hv.w * l4.w;
    }
    float z = mu + eps[idx] * __expf(0.5f * lv);
    const size_t XR = (size_t)BB * TT * DD;           // 3145728
    out[XR + idx] = mu;
    out[XR + (size_t)BB * ZZ + idx] = lv;
    out[XR + 2 * (size_t)BB * ZZ + idx] = z;
}

// ---------------- decoder init states: h0 = tanh(zW), c0 = tanh(zW) ----------------
__global__ void h0c0(const float* __restrict__ z, const float* __restrict__ Wh0,
                     const float* __restrict__ bh0, const float* __restrict__ Wc0,
                     const float* __restrict__ bc0, u16* __restrict__ A,
                     float* __restrict__ c)
{
    int idx = blockIdx.x * 256 + threadIdx.x;   // BB*HD
    int b = idx >> 10, j = idx & (HD - 1);
    const float* zr = z + ((size_t)b << 7);
    const float* w0 = Wh0 + j * ZZ;
    const float* w1 = Wc0 + j * ZZ;
    float a0 = bh0[j], a1 = bc0[j];
    for (int k = 0; k < ZZ; k += 4) {
        float4 zv  = *(const float4*)&zr[k];
        float4 wv0 = *(const float4*)&w0[k];
        float4 wv1 = *(const float4*)&w1[k];
        a0 += zv.x * wv0.x + zv.y * wv0.y + zv.z * wv0.z + zv.w * wv0.w;
        a1 += zv.x * wv1.x + zv.y * wv1.y + zv.z * wv1.z + zv.w * wv1.w;
    }
    A[(size_t)b * KD + j] = f2bf(tanh_(a0));
    c[idx] = tanh_(a1);
}

// ---------------- decoder x-col init: start token + zero pad ----------------
__global__ void init_dec(u16* __restrict__ A, const float* __restrict__ st)
{
    int idx = blockIdx.x * 256 + threadIdx.x;   // BB*64
    int b = idx >> 6, j = idx & 63;
    A[(size_t)b * KD + HD + j] = (j < DD) ? f2bf(st[j]) : (u16)0;
}

// ---------------- decoder LSTM pointwise ----------------
__global__ void ew_dec(const float* __restrict__ gates, const float* __restrict__ bias,
                       float* __restrict__ c, u16* __restrict__ A,
                       const float* __restrict__ x, int t)
{
    int idx = blockIdx.x * 256 + threadIdx.x;   // BB*HD
    int b = idx >> 10, j = idx & (HD - 1);
    const float* g = gates + ((size_t)b << 12);
    float iv = sigmf(g[j]            + bias[j]);
    float fv = sigmf(g[j + HD]       + bias[j + HD]);
    float gv = tanh_(g[j + 2 * HD]   + bias[j + 2 * HD]);
    float ov = sigmf(g[j + 3 * HD]   + bias[j + 3 * HD]);
    float cn = fv * c[idx] + iv * gv;
    float h  = ov * tanh_(cn);
    c[idx] = cn;
    A[(size_t)b * KD + j] = f2bf(h);
    // decoder input for step t+1 is x[:, t, :]
    if (j < DD && t < TT - 1)
        A[(size_t)b * KD + HD + j] = f2bf(x[((size_t)b * TT + t) * DD + j]);
}

// ---------------- output projection: x_recon[:,t,:] = h @ Wout^T + bout ----------------
__global__ void outproj(const u16* __restrict__ A, const float* __restrict__ Wout,
                        const float* __restrict__ bout, float* __restrict__ xr, int t)
{
    int idx = blockIdx.x * 256 + threadIdx.x;   // BB*DD
    int b = idx / DD, d = idx - b * DD;
    const u16* h = A + (size_t)b * KD;
    const float* w = Wout + d * HD;
    float acc = bout[d];
    for (int k = 0; k < HD; k += 8) {
        uint4 hv = *(const uint4*)&h[k];
        const u16* hs = (const u16*)&hv;
        float4 w0 = *(const float4*)&w[k];
        float4 w1 = *(const float4*)&w[k + 4];
        acc += bf2f(hs[0]) * w0.x + bf2f(hs[1]) * w0.y + bf2f(hs[2]) * w0.z + bf2f(hs[3]) * w0.w;
        acc += bf2f(hs[4]) * w1.x + bf2f(hs[5]) * w1.y + bf2f(hs[6]) * w1.z + bf2f(hs[7]) * w1.w;
    }
    xr[((size_t)b * TT + t) * DD + d] = acc;
}

// ---------------- launch ----------------
extern "C" void kernel_launch(void* const* d_in, const int* in_sizes, int n_in,
                              void* d_out, int out_size, void* d_ws, size_t ws_size,
                              hipStream_t stream)
{
    const float* x    = (const float*)d_in[0];
    const int*   lens = (const int*)d_in[1];
    const float* eps  = (const float*)d_in[2];
    const float* Wihe = (const float*)d_in[3];
    const float* Whhe = (const float*)d_in[4];
    const float* be   = (const float*)d_in[5];
    const float* Wmu  = (const float*)d_in[6];
    const float* bmu  = (const float*)d_in[7];
    const float* Wlv  = (const float*)d_in[8];
    const float* blv  = (const float*)d_in[9];
    const float* Wh0  = (const float*)d_in[10];
    const float* bh0  = (const float*)d_in[11];
    const float* Wc0  = (const float*)d_in[12];
    const float* bc0  = (const float*)d_in[13];
    const float* st   = (const float*)d_in[14];
    const float* Wihd = (const float*)d_in[15];
    const float* Whhd = (const float*)d_in[16];
    const float* bd   = (const float*)d_in[17];
    const float* Wout = (const float*)d_in[18];
    const float* bout = (const float*)d_in[19];
    float* out = (float*)d_out;

    char* ws = (char*)d_ws;
    u16*   WCE = (u16*)(ws + 0);              //  2048*576*2   = 2,359,296
    u16*   WCD = (u16*)(ws + 2359296);        //  4096*1088*2  = 8,912,896
    u16*   AE  = (u16*)(ws + 11272192);       //  8192*576*2   = 9,437,184
    u16*   AD  = (u16*)(ws + 20709376);       //  8192*1088*2  = 17,825,792
    float* CE  = (float*)(ws + 38535168);     //  8192*512*4   = 16,777,216
    float* CD  = (float*)(ws + 55312384);     //  8192*1024*4  = 33,554,432
    float* HN  = (float*)(ws + 88866816);     //  8192*512*4   = 16,777,216
    float* GT  = (float*)(ws + 105644032);    //  8192*4096*4  = 134,217,728  (end ~240MB)

    prep_w<<<(2048 * KE + 255) / 256, 256, 0, stream>>>(Whhe, Wihe, WCE, HE, KE, 2048 * KE);
    prep_w<<<(4096 * KD + 255) / 256, 256, 0, stream>>>(Whhd, Wihd, WCD, HD, KD, 4096 * KD);
    init_enc<<<(BB * KE) / 256, 256, 0, stream>>>(AE, CE, x);

    for (int t = 0; t < TT; ++t) {
        gemm_bt<<<dim3(BB / 128, 2048 / 128), 256, 0, stream>>>(AE, WCE, GT, 2048, KE);
        ew_enc<<<(BB * HE) / 256, 256, 0, stream>>>(GT, be, CE, AE, HN, lens, x, t);
    }

    muvz<<<(BB * ZZ) / 256, 256, 0, stream>>>(HN, Wmu, bmu, Wlv, blv, eps, out);
    const float* zptr = out + (size_t)BB * TT * DD + 2 * (size_t)BB * ZZ;
    h0c0<<<(BB * HD) / 256, 256, 0, stream>>>(zptr, Wh0, bh0, Wc0, bc0, AD, CD);
    init_dec<<<(BB * 64) / 256, 256, 0, stream>>>(AD, st);

    for (int t = 0; t < TT; ++t) {
        gemm_bt<<<dim3(BB / 128, 4096 / 128), 256, 0, stream>>>(AD, WCD, GT, 4096, KD);
        ew_dec<<<(BB * HD) / 256, 256, 0, stream>>>(GT, bd, CD, AD, x, t);
        outproj<<<(BB * DD) / 256, 256, 0, stream>>>(AD, Wout, bout, out, t);
    }
}

// Round 4
// 5255.557 us; speedup vs baseline: 1.8645x; 1.8645x over previous
//
#include <hip/hip_runtime.h>
#include <hip/hip_bf16.h>

// ---------------- problem constants ----------------
#define BB 8192
#define TT 32
#define DD 12
#define ZZ 128
#define HE 512
#define HD 1024
#define KE 576    // 512 + 12 + pad -> multiple of 64
#define KD 1088   // 1024 + 12 + pad

typedef unsigned short u16;
typedef __attribute__((ext_vector_type(8))) short bf16x8;
typedef __attribute__((ext_vector_type(4))) float f32x4;

__device__ __forceinline__ u16 f2bf(float f) {
    __hip_bfloat16 h = __float2bfloat16(f);
    return *reinterpret_cast<u16*>(&h);
}
__device__ __forceinline__ float bf2f(u16 u) {
    __hip_bfloat16 h;
    *reinterpret_cast<u16*>(&h) = u;
    return __bfloat162float(h);
}
__device__ __forceinline__ float sigmf(float x) { return 1.f / (1.f + __expf(-x)); }
__device__ __forceinline__ float tanh_(float x) {
    float ax = fabsf(x);
    float e = __expf(-2.f * ax);
    float t = (1.f - e) / (1.f + e);
    return copysignf(t, x);
}

__device__ __forceinline__ void gload_lds16(const void* g, void* l) {
    __builtin_amdgcn_global_load_lds(
        (const __attribute__((address_space(1))) void*)g,
        (__attribute__((address_space(3))) void*)l,
        16, 0, 0);
}

// ---------------- fused GEMM: C[M][N] = A[M][K] * W[N][K]^T ----------------
// MODE 0: plain fp32 C store.
// MODE 1: encoder LSTM epilogue (gate-interleaved W', writes h->Aout bf16,
//         c-state fp32 in place, hn capture bf16, stages x[:,t+1,:]).
// MODE 2: decoder LSTM epilogue (same, stages x[:,t,:], no hn).
template<int MODE>
__global__ __launch_bounds__(256, 2)
void gemm_fused(const u16* __restrict__ A, const u16* __restrict__ W,
                float* __restrict__ C, int N, int K, int H,
                float* __restrict__ Cst, u16* __restrict__ Aout,
                const float* __restrict__ bias, const int* __restrict__ lens,
                u16* __restrict__ HN, const float* __restrict__ X, int t)
{
    __shared__ u16 As[128 * 64];
    __shared__ u16 Ws[128 * 64];
    const int tid  = threadIdx.x;
    const int lane = tid & 63;
    const int wave = tid >> 6;
    const int wm = wave >> 1, wn = wave & 1;
    const int bm = blockIdx.x * 128;
    const int bn = blockIdx.y * 128;

    f32x4 acc[4][4] = {};

    const int lrow = lane >> 3;        // 0..7
    const int lcol = (lane & 7) * 8;   // 0,8,..,56

    for (int kt = 0; kt < K; kt += 64) {
#pragma unroll
        for (int c2 = 0; c2 < 4; ++c2) {
            const int chunk = wave * 4 + c2;        // 0..15
            const int row = chunk * 8 + lrow;       // 0..127
            gload_lds16(A + (size_t)(bm + row) * K + kt + lcol, &As[chunk * 512]);
            gload_lds16(W + (size_t)(bn + row) * K + kt + lcol, &Ws[chunk * 512]);
        }
        __syncthreads();
#pragma unroll
        for (int ks = 0; ks < 2; ++ks) {
            bf16x8 af[4], wf[4];
            const int ko = ks * 32 + (lane >> 4) * 8;
            const int rA = wm * 64 + (lane & 15);
            const int rW = wn * 64 + (lane & 15);
#pragma unroll
            for (int i = 0; i < 4; ++i)
                af[i] = *(const bf16x8*)&As[(rA + i * 16) * 64 + ko];
#pragma unroll
            for (int i = 0; i < 4; ++i)
                wf[i] = *(const bf16x8*)&Ws[(rW + i * 16) * 64 + ko];
#pragma unroll
            for (int i = 0; i < 4; ++i)
#pragma unroll
                for (int j = 0; j < 4; ++j)
                    acc[i][j] = __builtin_amdgcn_mfma_f32_16x16x32_bf16(
                        af[i], wf[j], acc[i][j], 0, 0, 0);
        }
        __syncthreads();
    }

    if (MODE == 0) {
        // C/D layout: col = lane&15, row = (lane>>4)*4 + reg
        const int r0 = bm + wm * 64 + (lane >> 4) * 4;
        const int c0 = bn + wn * 64 + (lane & 15);
#pragma unroll
        for (int i = 0; i < 4; ++i)
#pragma unroll
            for (int j = 0; j < 4; ++j) {
                float* Cp = C + (size_t)(r0 + i * 16) * N + c0 + j * 16;
#pragma unroll
                for (int q = 0; q < 4; ++q)
                    Cp[(size_t)q * N] = acc[i][j][q];
            }
    } else {
        // gate-interleaved: fragment j = gate j for hcol below
        const int hcol = ((bn >> 6) + wn) * 16 + (lane & 15);
        const float bI = bias[hcol];
        const float bF = bias[H + hcol];
        const float bG = bias[2 * H + hcol];
        const float bO = bias[3 * H + hcol];
#pragma unroll
        for (int i = 0; i < 4; ++i) {
            const int rbase = bm + wm * 64 + i * 16 + (lane >> 4) * 4;
#pragma unroll
            for (int q = 0; q < 4; ++q) {
                const int r = rbase + q;
                float iv = sigmf(acc[i][0][q] + bI);
                float fv = sigmf(acc[i][1][q] + bF);
                float gv = tanh_(acc[i][2][q] + bG);
                float ov = sigmf(acc[i][3][q] + bO);
                float cn = fv * Cst[(size_t)r * H + hcol] + iv * gv;
                float h  = ov * tanh_(cn);
                Cst[(size_t)r * H + hcol] = cn;
                Aout[(size_t)r * K + hcol] = f2bf(h);
                if (MODE == 1) {
                    int L = lens[r]; L = (L < 1) ? 1 : (L > TT ? TT : L);
                    if (t == L - 1) HN[(size_t)r * H + hcol] = f2bf(h);
                }
            }
        }
        // stage next-step x into Aout x-columns (one block column does it)
        const int tx = (MODE == 1) ? t + 1 : t;
        if (bn == 0 && tx < TT) {
            for (int ii = tid; ii < 128 * DD; ii += 256) {
                const int rr = ii / DD, d = ii - rr * DD;
                const int r = bm + rr;
                Aout[(size_t)r * K + H + d] =
                    f2bf(X[((size_t)r * TT + tx) * DD + d]);
            }
        }
    }
}

// ---------------- gate-interleaved weight concat ----------------
// n' = 64*(j>>4) + 16*gate + (j&15); row = [Whh[gate*H+j] | Wih[gate*H+j] | 0]
__global__ void prep_wg(const float* __restrict__ Whh, const float* __restrict__ Wih,
                        u16* __restrict__ dst, int H, int Kc, int total)
{
    int idx = blockIdx.x * 256 + threadIdx.x;
    if (idx >= total) return;
    int np = idx / Kc, k = idx - np * Kc;
    int jblk = np >> 6, rem = np & 63;
    int gate = rem >> 4, jl = rem & 15;
    int j = jblk * 16 + jl;
    int srow = gate * H + j;
    float v = 0.f;
    if (k < H) v = Whh[(size_t)srow * H + k];
    else if (k < H + DD) v = Wih[srow * DD + (k - H)];
    dst[idx] = f2bf(v);
}

// ---------------- plain stacked concat (bf16): [W0; W1], both [rows0][K] ----
__global__ void prep_cat(const float* __restrict__ W0, const float* __restrict__ W1,
                         u16* __restrict__ dst, int rows0, int K, int total)
{
    int idx = blockIdx.x * 256 + threadIdx.x;
    if (idx >= total) return;
    int n = idx / K, k = idx - n * K;
    float v = (n < rows0) ? W0[(size_t)n * K + k] : W1[(size_t)(n - rows0) * K + k];
    dst[idx] = f2bf(v);
}

__global__ void prep_bf(const float* __restrict__ src, u16* __restrict__ dst, int total)
{
    int idx = blockIdx.x * 256 + threadIdx.x;
    if (idx < total) dst[idx] = f2bf(src[idx]);
}

// ---------------- encoder init: h=0, x col = x[:,0,:], pad=0; c=0 ----------------
__global__ void init_enc(u16* __restrict__ A, float* __restrict__ c, const float* __restrict__ x)
{
    int idx = blockIdx.x * 256 + threadIdx.x;   // BB*KE
    int b = idx / KE, j = idx - b * KE;
    u16 v = 0;
    if (j >= HE && j < HE + DD) v = f2bf(x[(size_t)b * (TT * DD) + (j - HE)]);
    A[idx] = v;
    if (j < HE) c[(size_t)b * HE + j] = 0.f;
}

// ---------------- z: from MV = [mu | lv] fp32; writes outputs + bf16 z ----------------
__global__ void z_comp(const float* __restrict__ MV, const float* __restrict__ bmu,
                       const float* __restrict__ blv, const float* __restrict__ eps,
                       float* __restrict__ out, u16* __restrict__ Zbf)
{
    int idx = blockIdx.x * 256 + threadIdx.x;   // BB*ZZ
    int b = idx >> 7, zc = idx & (ZZ - 1);
    float mu = MV[(size_t)b * 256 + zc] + bmu[zc];
    float lv = MV[(size_t)b * 256 + ZZ + zc] + blv[zc];
    float z = mu + eps[idx] * __expf(0.5f * lv);
    const size_t XR = (size_t)BB * TT * DD;
    out[XR + idx] = mu;
    out[XR + (size_t)BB * ZZ + idx] = lv;
    out[XR + 2 * (size_t)BB * ZZ + idx] = z;
    Zbf[idx] = f2bf(z);
}

// ---------------- decoder state init from HC = [h0pre | c0pre] fp32 ----------------
__global__ void hc_init(const float* __restrict__ HC, const float* __restrict__ bh0,
                        const float* __restrict__ bc0, u16* __restrict__ A,
                        float* __restrict__ c)
{
    int idx = blockIdx.x * 256 + threadIdx.x;   // BB*HD
    int b = idx >> 10, j = idx & (HD - 1);
    float h0 = tanh_(HC[(size_t)b * 2048 + j] + bh0[j]);
    float c0 = tanh_(HC[(size_t)b * 2048 + HD + j] + bc0[j]);
    A[(size_t)b * KD + j] = f2bf(h0);
    c[idx] = c0;
}

// ---------------- decoder x-col init: start token + zero pad ----------------
__global__ void init_dec(u16* __restrict__ A, const float* __restrict__ st)
{
    int idx = blockIdx.x * 256 + threadIdx.x;   // BB*64
    int b = idx >> 6, j = idx & 63;
    A[(size_t)b * KD + HD + j] = (j < DD) ? f2bf(st[j]) : (u16)0;
}

// ---------------- output projection: wave per row, butterfly reduce ----------------
__global__ void outproj2(const u16* __restrict__ A, const u16* __restrict__ Wb,
                         const float* __restrict__ bout, float* __restrict__ xr, int t)
{
    int gid = blockIdx.x * 256 + threadIdx.x;
    int b = gid >> 6;
    int lane = threadIdx.x & 63;
    const u16* h = A + (size_t)b * KD;
    const int k0 = lane * 16;
    bf16x8 h0 = *(const bf16x8*)&h[k0];
    bf16x8 h1 = *(const bf16x8*)&h[k0 + 8];
    float hv[16];
#pragma unroll
    for (int k = 0; k < 8; ++k) { hv[k] = bf2f((u16)h0[k]); hv[k + 8] = bf2f((u16)h1[k]); }
    float acc[DD];
#pragma unroll
    for (int d = 0; d < DD; ++d) {
        const u16* w = Wb + d * HD + k0;
        bf16x8 w0 = *(const bf16x8*)&w[0];
        bf16x8 w1 = *(const bf16x8*)&w[8];
        float a = 0.f;
#pragma unroll
        for (int k = 0; k < 8; ++k)
            a += hv[k] * bf2f((u16)w0[k]) + hv[k + 8] * bf2f((u16)w1[k]);
        acc[d] = a;
    }
#pragma unroll
    for (int off = 32; off > 0; off >>= 1)
#pragma unroll
        for (int d = 0; d < DD; ++d)
            acc[d] += __shfl_xor(acc[d], off);
    if (lane < DD)
        xr[((size_t)b * TT + t) * DD + lane] = acc[lane] + bout[lane];
}

// ---------------- launch ----------------
extern "C" void kernel_launch(void* const* d_in, const int* in_sizes, int n_in,
                              void* d_out, int out_size, void* d_ws, size_t ws_size,
                              hipStream_t stream)
{
    const float* x    = (const float*)d_in[0];
    const int*   lens = (const int*)d_in[1];
    const float* eps  = (const float*)d_in[2];
    const float* Wihe = (const float*)d_in[3];
    const float* Whhe = (const float*)d_in[4];
    const float* be   = (const float*)d_in[5];
    const float* Wmu  = (const float*)d_in[6];
    const float* bmu  = (const float*)d_in[7];
    const float* Wlv  = (const float*)d_in[8];
    const float* blv  = (const float*)d_in[9];
    const float* Wh0  = (const float*)d_in[10];
    const float* bh0  = (const float*)d_in[11];
    const float* Wc0  = (const float*)d_in[12];
    const float* bc0  = (const float*)d_in[13];
    const float* st   = (const float*)d_in[14];
    const float* Wihd = (const float*)d_in[15];
    const float* Whhd = (const float*)d_in[16];
    const float* bd   = (const float*)d_in[17];
    const float* Wout = (const float*)d_in[18];
    const float* bout = (const float*)d_in[19];
    float* out = (float*)d_out;

    char* ws = (char*)d_ws;
    size_t o = 0;
    u16*   WCE = (u16*)(ws + o); o += (size_t)2048 * KE * 2;   // 2,359,296
    u16*   WCD = (u16*)(ws + o); o += (size_t)4096 * KD * 2;   // 8,912,896
    u16*   WMV = (u16*)(ws + o); o += (size_t)256 * 512 * 2;   // 262,144
    u16*   WHC = (u16*)(ws + o); o += (size_t)2048 * 128 * 2;  // 524,288
    u16*   WOB = (u16*)(ws + o); o += 32768;                   // 12*1024*2 padded
    u16*   AE0 = (u16*)(ws + o); o += (size_t)BB * KE * 2;     // 9,437,184
    u16*   AE1 = (u16*)(ws + o); o += (size_t)BB * KE * 2;
    u16*   AD0 = (u16*)(ws + o); o += (size_t)BB * KD * 2;     // 17,825,792
    u16*   AD1 = (u16*)(ws + o); o += (size_t)BB * KD * 2;
    float* CE  = (float*)(ws + o); o += (size_t)BB * HE * 4;   // 16,777,216
    float* CD  = (float*)(ws + o); o += (size_t)BB * HD * 4;   // 33,554,432
    u16*   HNb = (u16*)(ws + o); o += (size_t)BB * HE * 2;     // 8,388,608
    float* MV  = (float*)(ws + o); o += (size_t)BB * 256 * 4;  // 8,388,608
    u16*   Zbf = (u16*)(ws + o); o += (size_t)BB * ZZ * 2;     // 2,097,152
    float* HC  = (float*)(ws + o); o += (size_t)BB * 2048 * 4; // 67,108,864
    // total ~203 MB

    prep_wg<<<(2048 * KE + 255) / 256, 256, 0, stream>>>(Whhe, Wihe, WCE, HE, KE, 2048 * KE);
    prep_wg<<<(4096 * KD + 255) / 256, 256, 0, stream>>>(Whhd, Wihd, WCD, HD, KD, 4096 * KD);
    prep_cat<<<(256 * 512 + 255) / 256, 256, 0, stream>>>(Wmu, Wlv, WMV, ZZ, HE, 256 * 512);
    prep_cat<<<(2048 * 128 + 255) / 256, 256, 0, stream>>>(Wh0, Wc0, WHC, HD, ZZ, 2048 * 128);
    prep_bf<<<(12 * HD + 255) / 256, 256, 0, stream>>>(Wout, WOB, 12 * HD);
    init_enc<<<(BB * KE) / 256, 256, 0, stream>>>(AE0, CE, x);

    u16* AE[2] = {AE0, AE1};
    for (int t = 0; t < TT; ++t) {
        gemm_fused<1><<<dim3(BB / 128, 2048 / 128), 256, 0, stream>>>(
            AE[t & 1], WCE, nullptr, 2048, KE, HE, CE, AE[1 - (t & 1)],
            be, lens, HNb, x, t);
    }

    gemm_fused<0><<<dim3(BB / 128, 256 / 128), 256, 0, stream>>>(
        HNb, WMV, MV, 256, 512, 0, nullptr, nullptr, nullptr, nullptr, nullptr, nullptr, 0);
    z_comp<<<(BB * ZZ) / 256, 256, 0, stream>>>(MV, bmu, blv, eps, out, Zbf);
    gemm_fused<0><<<dim3(BB / 128, 2048 / 128), 256, 0, stream>>>(
        Zbf, WHC, HC, 2048, 128, 0, nullptr, nullptr, nullptr, nullptr, nullptr, nullptr, 0);
    hc_init<<<(BB * HD) / 256, 256, 0, stream>>>(HC, bh0, bc0, AD0, CD);
    init_dec<<<(BB * 64) / 256, 256, 0, stream>>>(AD0, st);

    u16* AD[2] = {AD0, AD1};
    for (int t = 0; t < TT; ++t) {
        gemm_fused<2><<<dim3(BB / 128, 4096 / 128), 256, 0, stream>>>(
            AD[t & 1], WCD, nullptr, 4096, KD, HD, CD, AD[1 - (t & 1)],
            bd, nullptr, nullptr, x, t);
        outproj2<<<(BB * 64) / 256, 256, 0, stream>>>(AD[1 - (t & 1)], WOB, bout, out, t);
    }
}

// Round 5
// 5053.909 us; speedup vs baseline: 1.9389x; 1.0399x over previous
//
#include <hip/hip_runtime.h>
#include <hip/hip_bf16.h>

// ---------------- problem constants ----------------
#define BB 8192
#define TT 32
#define DD 12
#define ZZ 128
#define HE 512
#define HD 1024
#define KEp 640    // 512 + 12 -> padded to 10 x 64
#define KDp 1152   // 1024 + 12 -> padded to 18 x 64

typedef unsigned short u16;
typedef __attribute__((ext_vector_type(8))) short bf16x8;
typedef __attribute__((ext_vector_type(4))) float f32x4;

__device__ __forceinline__ u16 f2bf(float f) {
    __hip_bfloat16 h = __float2bfloat16(f);
    return *reinterpret_cast<u16*>(&h);
}
__device__ __forceinline__ float bf2f(u16 u) {
    __hip_bfloat16 h;
    *reinterpret_cast<u16*>(&h) = u;
    return __bfloat162float(h);
}
__device__ __forceinline__ float sigmf(float x) { return 1.f / (1.f + __expf(-x)); }
__device__ __forceinline__ float tanh_(float x) {
    float ax = fabsf(x);
    float e = __expf(-2.f * ax);
    float t = (1.f - e) / (1.f + e);
    return copysignf(t, x);
}

__device__ __forceinline__ void gload_lds16(const void* g, void* l) {
    __builtin_amdgcn_global_load_lds(
        (const __attribute__((address_space(1))) void*)g,
        (__attribute__((address_space(3))) void*)l,
        16, 0, 0);
}

#define BAR() asm volatile("s_barrier" ::: "memory")
#define VMCNT(n) asm volatile("s_waitcnt vmcnt(" #n ")" ::: "memory")

// ============================================================================
// 256x256 8-phase counted-vmcnt GEMM with fused LSTM epilogue.
// C[M][N] = A[M][Kp] * W[N][Kp]^T, A/W bf16 row-major, K padded to 64*NT.
// 512 threads = 8 waves (2M x 4N); per-wave output 128x64.
// LDS: 8 regions of [256 rows][32 k] bf16 (16KB each) = 128KB:
//   region(dbuf, mat, khalf). Row stride 64B -> each wave's 4x ds_read_b128
//   fragment read covers a contiguous 1KB -> conflict-free.
// Phase p of K-tile group (kh, mh): reads A rows [wm*128+mh*64,+64), B all 4
//   j-frags (B regs reused across mh). Retirement: dbuf.kh0 after phase 1 (of
//   4), dbuf.kh1 after phase 3. Staging map (iter n, tiles 2n->d0, 2n+1->d1):
//   p0: T(2n+1).A.kh1->d1  p1: T(2n+1).B.kh1->d1   (d1.kh1 retired prev p7)
//   p2: T(2n+2).A.kh0->d0  p3: T(2n+2).B.kh0->d0   (d0.kh0 retired at p1)
//   p4: T(2n+2).A.kh1->d0  p5: T(2n+2).B.kh1->d0   (d0.kh1 retired at p3)
//   p6: T(2n+3).A.kh0->d1  p7: T(2n+3).B.kh0->d1   (d1.kh0 retired at p5)
//   vmcnt(4) before trailing barrier of p3 (forces tile 2n+1 resident for
//   p4..p7) and of p7 (forces tile 2n+2 resident for next iter p0..p3).
// MODE 1: encoder LSTM epilogue (+ hn capture + stage x[t+1])
// MODE 2: decoder LSTM epilogue (+ stage x[t])
// ============================================================================
#define REGION(dd, mat, kh) (((dd)*4 + (mat)*2 + (kh)) * 8192)

#define STAGE(dd, mat, kh, ktile) do { \
    const u16* Gp_ = (mat) ? W : A; \
    const int rb_ = (mat) ? bn : bm; \
    const int kc_ = (ktile)*64 + (kh)*32 + (tid & 3)*8; \
    u16* dst_ = &lds[REGION(dd, mat, kh) + tid*8]; \
    const u16* s0_ = Gp_ + (size_t)(rb_ + (tid >> 2)) * Kp + kc_; \
    gload_lds16(s0_, dst_); \
    gload_lds16(s0_ + (size_t)128 * Kp, dst_ + 4096); \
} while (0)

#define LDA4(mh, dd, kh) do { \
    const u16* bp_ = &lds[REGION(dd, 0, kh)]; \
    _Pragma("unroll") \
    for (int i_ = 0; i_ < 4; ++i_) \
        af[i_] = *(const bf16x8*)&bp_[(wm*128 + (mh)*64 + i_*16 + (lane & 15))*32 + (lane >> 4)*8]; \
} while (0)

#define LDB4(dd, kh) do { \
    const u16* bp_ = &lds[REGION(dd, 1, kh)]; \
    _Pragma("unroll") \
    for (int j_ = 0; j_ < 4; ++j_) \
        bf[j_] = *(const bf16x8*)&bp_[(wn*64 + j_*16 + (lane & 15))*32 + (lane >> 4)*8]; \
} while (0)

#define MFMA16(mh) do { \
    __builtin_amdgcn_s_setprio(1); \
    _Pragma("unroll") \
    for (int i_ = 0; i_ < 4; ++i_) \
    _Pragma("unroll") \
    for (int j_ = 0; j_ < 4; ++j_) \
        acc[(mh)*4 + i_][j_] = __builtin_amdgcn_mfma_f32_16x16x32_bf16( \
            af[i_], bf[j_], acc[(mh)*4 + i_][j_], 0, 0, 0); \
    __builtin_amdgcn_s_setprio(0); \
} while (0)

template<int MODE>
__global__ __launch_bounds__(512, 2)
void gemm256(const u16* __restrict__ A, const u16* __restrict__ W,
             int Kp, int NT, int H,
             float* __restrict__ Cst, u16* __restrict__ Aout,
             const float* __restrict__ bias, const int* __restrict__ lens,
             u16* __restrict__ HN, const float* __restrict__ X, int t)
{
    extern __shared__ u16 lds[];
    const int tid  = threadIdx.x;
    const int lane = tid & 63;
    const int wid  = tid >> 6;
    const int wm = wid >> 2, wn = wid & 3;
    const int bm = blockIdx.x * 256;
    const int bn = blockIdx.y * 256;

    f32x4 acc[8][4] = {};
    bf16x8 af[4], bf[4];

    // prologue: T0 fully + T1.kh0 (6 half-tiles, 12 loads)
    STAGE(0, 0, 0, 0); STAGE(0, 1, 0, 0);
    STAGE(0, 0, 1, 0); STAGE(0, 1, 1, 0);
    STAGE(1, 0, 0, 1); STAGE(1, 1, 0, 1);
    VMCNT(4);              // T0 resident; T1.kh0 may be in flight
    BAR();

    const int NI = NT >> 1;
    for (int n = 0; n < NI; ++n) {
        const int t1 = 2*n + 1, t2 = 2*n + 2, t3 = 2*n + 3;
        const bool more = (t2 < NT);   // false only on last iteration
        // p0: d0.kh0.mh0
        LDA4(0, 0, 0); LDB4(0, 0);
        STAGE(1, 0, 1, t1);
        BAR(); MFMA16(0); BAR();
        // p1: d0.kh0.mh1 (reuse B)
        LDA4(1, 0, 0);
        STAGE(1, 1, 1, t1);
        BAR(); MFMA16(1); BAR();
        // p2: d0.kh1.mh0
        LDA4(0, 0, 1); LDB4(0, 1);
        if (more) STAGE(0, 0, 0, t2);
        BAR(); MFMA16(0); BAR();
        // p3: d0.kh1.mh1 ; vmcnt gate for tile t1
        LDA4(1, 0, 1);
        if (more) STAGE(0, 1, 0, t2);
        BAR(); MFMA16(1);
        if (n == NI - 1) { VMCNT(0); } else { VMCNT(4); }
        BAR();
        // p4: d1.kh0.mh0
        LDA4(0, 1, 0); LDB4(1, 0);
        if (more) STAGE(0, 0, 1, t2);
        BAR(); MFMA16(0); BAR();
        // p5: d1.kh0.mh1
        LDA4(1, 1, 0);
        if (more) STAGE(0, 1, 1, t2);
        BAR(); MFMA16(1); BAR();
        // p6: d1.kh1.mh0
        LDA4(0, 1, 1); LDB4(1, 1);
        if (more) STAGE(1, 0, 0, t3);
        BAR(); MFMA16(0); BAR();
        // p7: d1.kh1.mh1 ; vmcnt gate for tile t2
        LDA4(1, 1, 1);
        if (more) STAGE(1, 1, 0, t3);
        BAR(); MFMA16(1);
        if (n < NI - 1) { VMCNT(4); }
        BAR();
    }

    // ---- fused LSTM epilogue (gate-interleaved weights) ----
    const int hcol = ((bn >> 6) + wn) * 16 + (lane & 15);
    const float bI = bias[hcol];
    const float bF = bias[H + hcol];
    const float bG = bias[2 * H + hcol];
    const float bO = bias[3 * H + hcol];
#pragma unroll
    for (int i = 0; i < 8; ++i) {
        const int rbase = bm + wm * 128 + i * 16 + (lane >> 4) * 4;
#pragma unroll
        for (int q = 0; q < 4; ++q) {
            const int r = rbase + q;
            float iv = sigmf(acc[i][0][q] + bI);
            float fv = sigmf(acc[i][1][q] + bF);
            float gv = tanh_(acc[i][2][q] + bG);
            float ov = sigmf(acc[i][3][q] + bO);
            float cn = fv * Cst[(size_t)r * H + hcol] + iv * gv;
            float h  = ov * tanh_(cn);
            Cst[(size_t)r * H + hcol] = cn;
            Aout[(size_t)r * Kp + hcol] = f2bf(h);
            if (MODE == 1) {
                int L = lens[r]; L = (L < 1) ? 1 : (L > TT ? TT : L);
                if (t == L - 1) HN[(size_t)r * H + hcol] = f2bf(h);
            }
        }
    }
    // stage next-step x into Aout x-columns (one block column does it)
    const int tx = (MODE == 1) ? t + 1 : t;
    if (bn == 0 && tx < TT) {
        for (int ii = tid; ii < 256 * DD; ii += 512) {
            const int rr = ii / DD, d = ii - rr * DD;
            const int r = bm + rr;
            Aout[(size_t)r * Kp + H + d] = f2bf(X[((size_t)r * TT + tx) * DD + d]);
        }
    }
}

// ---------------- plain 128x128 GEMM (small matmuls): C = A * W^T ----------
__global__ __launch_bounds__(256, 2)
void gemm_bt(const u16* __restrict__ A, const u16* __restrict__ W,
             float* __restrict__ C, int N, int K)
{
    __shared__ u16 As[128 * 64];
    __shared__ u16 Ws[128 * 64];
    const int tid  = threadIdx.x;
    const int lane = tid & 63;
    const int wave = tid >> 6;
    const int wm = wave >> 1, wn = wave & 1;
    const int bm = blockIdx.x * 128;
    const int bn = blockIdx.y * 128;

    f32x4 acc[4][4] = {};
    const int lrow = lane >> 3;
    const int lcol = (lane & 7) * 8;

    for (int kt = 0; kt < K; kt += 64) {
#pragma unroll
        for (int c2 = 0; c2 < 4; ++c2) {
            const int chunk = wave * 4 + c2;
            const int row = chunk * 8 + lrow;
            gload_lds16(A + (size_t)(bm + row) * K + kt + lcol, &As[chunk * 512]);
            gload_lds16(W + (size_t)(bn + row) * K + kt + lcol, &Ws[chunk * 512]);
        }
        __syncthreads();
#pragma unroll
        for (int ks = 0; ks < 2; ++ks) {
            bf16x8 af[4], wf[4];
            const int ko = ks * 32 + (lane >> 4) * 8;
            const int rA = wm * 64 + (lane & 15);
            const int rW = wn * 64 + (lane & 15);
#pragma unroll
            for (int i = 0; i < 4; ++i)
                af[i] = *(const bf16x8*)&As[(rA + i * 16) * 64 + ko];
#pragma unroll
            for (int i = 0; i < 4; ++i)
                wf[i] = *(const bf16x8*)&Ws[(rW + i * 16) * 64 + ko];
#pragma unroll
            for (int i = 0; i < 4; ++i)
#pragma unroll
                for (int j = 0; j < 4; ++j)
                    acc[i][j] = __builtin_amdgcn_mfma_f32_16x16x32_bf16(
                        af[i], wf[j], acc[i][j], 0, 0, 0);
        }
        __syncthreads();
    }
    const int r0 = bm + wm * 64 + (lane >> 4) * 4;
    const int c0 = bn + wn * 64 + (lane & 15);
#pragma unroll
    for (int i = 0; i < 4; ++i)
#pragma unroll
        for (int j = 0; j < 4; ++j) {
            float* Cp = C + (size_t)(r0 + i * 16) * N + c0 + j * 16;
#pragma unroll
            for (int q = 0; q < 4; ++q)
                Cp[(size_t)q * N] = acc[i][j][q];
        }
}

// ---------------- gate-interleaved weight concat (padded K) ----------------
// n' = 64*(j>>4) + 16*gate + (j&15); row = [Whh[gate*H+j] | Wih[gate*H+j] | 0]
__global__ void prep_wg(const float* __restrict__ Whh, const float* __restrict__ Wih,
                        u16* __restrict__ dst, int H, int Kc, int total)
{
    int idx = blockIdx.x * 256 + threadIdx.x;
    if (idx >= total) return;
    int np = idx / Kc, k = idx - np * Kc;
    int jblk = np >> 6, rem = np & 63;
    int gate = rem >> 4, jl = rem & 15;
    int j = jblk * 16 + jl;
    int srow = gate * H + j;
    float v = 0.f;
    if (k < H) v = Whh[(size_t)srow * H + k];
    else if (k < H + DD) v = Wih[srow * DD + (k - H)];
    dst[idx] = f2bf(v);
}

// ---------------- plain stacked concat (bf16): [W0; W1] ----------------
__global__ void prep_cat(const float* __restrict__ W0, const float* __restrict__ W1,
                         u16* __restrict__ dst, int rows0, int K, int total)
{
    int idx = blockIdx.x * 256 + threadIdx.x;
    if (idx >= total) return;
    int n = idx / K, k = idx - n * K;
    float v = (n < rows0) ? W0[(size_t)n * K + k] : W1[(size_t)(n - rows0) * K + k];
    dst[idx] = f2bf(v);
}

__global__ void prep_bf(const float* __restrict__ src, u16* __restrict__ dst, int total)
{
    int idx = blockIdx.x * 256 + threadIdx.x;
    if (idx < total) dst[idx] = f2bf(src[idx]);
}

// ---------------- encoder init: h=0, x col = x[:,0,:], pad=0; c=0 ----------
__global__ void init_enc(u16* __restrict__ A, float* __restrict__ c, const float* __restrict__ x)
{
    int idx = blockIdx.x * 256 + threadIdx.x;   // BB*KEp
    int b = idx / KEp, j = idx - b * KEp;
    u16 v = 0;
    if (j >= HE && j < HE + DD) v = f2bf(x[(size_t)b * (TT * DD) + (j - HE)]);
    A[idx] = v;
    if (j < HE) c[(size_t)b * HE + j] = 0.f;
}

// ---------------- zero pad columns [lo, lo+n) of A[BB][ldK] ----------------
__global__ void zero_pads(u16* __restrict__ A, int ldK, int lo, int n, int total)
{
    int idx = blockIdx.x * 256 + threadIdx.x;
    if (idx >= total) return;
    int b = idx / n, j = idx - b * n;
    A[(size_t)b * ldK + lo + j] = 0;
}

// ---------------- z from MV = [mu | lv] fp32 ----------------
__global__ void z_comp(const float* __restrict__ MV, const float* __restrict__ bmu,
                       const float* __restrict__ blv, const float* __restrict__ eps,
                       float* __restrict__ out, u16* __restrict__ Zbf)
{
    int idx = blockIdx.x * 256 + threadIdx.x;   // BB*ZZ
    int b = idx >> 7, zc = idx & (ZZ - 1);
    float mu = MV[(size_t)b * 256 + zc] + bmu[zc];
    float lv = MV[(size_t)b * 256 + ZZ + zc] + blv[zc];
    float z = mu + eps[idx] * __expf(0.5f * lv);
    const size_t XR = (size_t)BB * TT * DD;
    out[XR + idx] = mu;
    out[XR + (size_t)BB * ZZ + idx] = lv;
    out[XR + 2 * (size_t)BB * ZZ + idx] = z;
    Zbf[idx] = f2bf(z);
}

// ---------------- decoder state init from HC = [h0pre | c0pre] -------------
__global__ void hc_init(const float* __restrict__ HC, const float* __restrict__ bh0,
                        const float* __restrict__ bc0, u16* __restrict__ A,
                        float* __restrict__ c)
{
    int idx = blockIdx.x * 256 + threadIdx.x;   // BB*HD
    int b = idx >> 10, j = idx & (HD - 1);
    float h0 = tanh_(HC[(size_t)b * 2048 + j] + bh0[j]);
    float c0 = tanh_(HC[(size_t)b * 2048 + HD + j] + bc0[j]);
    A[(size_t)b * KDp + j] = f2bf(h0);
    c[idx] = c0;
}

// ---------------- decoder x-col init: start token + zero pad to KDp --------
__global__ void init_dec(u16* __restrict__ A, const float* __restrict__ st)
{
    int idx = blockIdx.x * 256 + threadIdx.x;   // BB*128
    int b = idx >> 7, j = idx & 127;
    A[(size_t)b * KDp + HD + j] = (j < DD) ? f2bf(st[j]) : (u16)0;
}

// ---------------- output projection: wave per row, butterfly reduce --------
__global__ void outproj2(const u16* __restrict__ A, const u16* __restrict__ Wb,
                         const float* __restrict__ bout, float* __restrict__ xr, int t)
{
    int gid = blockIdx.x * 256 + threadIdx.x;
    int b = gid >> 6;
    int lane = threadIdx.x & 63;
    const u16* h = A + (size_t)b * KDp;
    const int k0 = lane * 16;
    bf16x8 h0 = *(const bf16x8*)&h[k0];
    bf16x8 h1 = *(const bf16x8*)&h[k0 + 8];
    float hv[16];
#pragma unroll
    for (int k = 0; k < 8; ++k) { hv[k] = bf2f((u16)h0[k]); hv[k + 8] = bf2f((u16)h1[k]); }
    float acc[DD];
#pragma unroll
    for (int d = 0; d < DD; ++d) {
        const u16* w = Wb + d * HD + k0;
        bf16x8 w0 = *(const bf16x8*)&w[0];
        bf16x8 w1 = *(const bf16x8*)&w[8];
        float a = 0.f;
#pragma unroll
        for (int k = 0; k < 8; ++k)
            a += hv[k] * bf2f((u16)w0[k]) + hv[k + 8] * bf2f((u16)w1[k]);
        acc[d] = a;
    }
#pragma unroll
    for (int off = 32; off > 0; off >>= 1)
#pragma unroll
        for (int d = 0; d < DD; ++d)
            acc[d] += __shfl_xor(acc[d], off);
    if (lane < DD)
        xr[((size_t)b * TT + t) * DD + lane] = acc[lane] + bout[lane];
}

// ---------------- launch ----------------
extern "C" void kernel_launch(void* const* d_in, const int* in_sizes, int n_in,
                              void* d_out, int out_size, void* d_ws, size_t ws_size,
                              hipStream_t stream)
{
    const float* x    = (const float*)d_in[0];
    const int*   lens = (const int*)d_in[1];
    const float* eps  = (const float*)d_in[2];
    const float* Wihe = (const float*)d_in[3];
    const float* Whhe = (const float*)d_in[4];
    const float* be   = (const float*)d_in[5];
    const float* Wmu  = (const float*)d_in[6];
    const float* bmu  = (const float*)d_in[7];
    const float* Wlv  = (const float*)d_in[8];
    const float* blv  = (const float*)d_in[9];
    const float* Wh0  = (const float*)d_in[10];
    const float* bh0  = (const float*)d_in[11];
    const float* Wc0  = (const float*)d_in[12];
    const float* bc0  = (const float*)d_in[13];
    const float* st   = (const float*)d_in[14];
    const float* Wihd = (const float*)d_in[15];
    const float* Whhd = (const float*)d_in[16];
    const float* bd   = (const float*)d_in[17];
    const float* Wout = (const float*)d_in[18];
    const float* bout = (const float*)d_in[19];
    float* out = (float*)d_out;

    char* ws = (char*)d_ws;
    size_t o = 0;
    u16*   WCE = (u16*)(ws + o); o += (size_t)2048 * KEp * 2;  //  2,621,440
    u16*   WCD = (u16*)(ws + o); o += (size_t)4096 * KDp * 2;  //  9,437,184
    u16*   WMV = (u16*)(ws + o); o += (size_t)256 * 512 * 2;   //    262,144
    u16*   WHC = (u16*)(ws + o); o += (size_t)2048 * 128 * 2;  //    524,288
    u16*   WOB = (u16*)(ws + o); o += 32768;
    u16*   AE0 = (u16*)(ws + o); o += (size_t)BB * KEp * 2;    // 10,485,760
    u16*   AE1 = (u16*)(ws + o); o += (size_t)BB * KEp * 2;
    u16*   AD0 = (u16*)(ws + o); o += (size_t)BB * KDp * 2;    // 18,874,368
    u16*   AD1 = (u16*)(ws + o); o += (size_t)BB * KDp * 2;
    float* CE  = (float*)(ws + o); o += (size_t)BB * HE * 4;   // 16,777,216
    float* CD  = (float*)(ws + o); o += (size_t)BB * HD * 4;   // 33,554,432
    u16*   HNb = (u16*)(ws + o); o += (size_t)BB * HE * 2;     //  8,388,608
    float* MV  = (float*)(ws + o); o += (size_t)BB * 256 * 4;  //  8,388,608
    u16*   Zbf = (u16*)(ws + o); o += (size_t)BB * ZZ * 2;     //  2,097,152
    float* HC  = (float*)(ws + o); o += (size_t)BB * 2048 * 4; // 67,108,864
    // total ~216 MB

    hipFuncSetAttribute((const void*)gemm256<1>,
                        hipFuncAttributeMaxDynamicSharedMemorySize, 131072);
    hipFuncSetAttribute((const void*)gemm256<2>,
                        hipFuncAttributeMaxDynamicSharedMemorySize, 131072);

    prep_wg<<<(2048 * KEp + 255) / 256, 256, 0, stream>>>(Whhe, Wihe, WCE, HE, KEp, 2048 * KEp);
    prep_wg<<<(4096 * KDp + 255) / 256, 256, 0, stream>>>(Whhd, Wihd, WCD, HD, KDp, 4096 * KDp);
    prep_cat<<<(256 * 512 + 255) / 256, 256, 0, stream>>>(Wmu, Wlv, WMV, ZZ, HE, 256 * 512);
    prep_cat<<<(2048 * 128 + 255) / 256, 256, 0, stream>>>(Wh0, Wc0, WHC, HD, ZZ, 2048 * 128);
    prep_bf<<<(12 * HD + 255) / 256, 256, 0, stream>>>(Wout, WOB, 12 * HD);
    init_enc<<<(BB * KEp) / 256, 256, 0, stream>>>(AE0, CE, x);
    zero_pads<<<(BB * 116 + 255) / 256, 256, 0, stream>>>(AE1, KEp, HE + DD, 116, BB * 116);
    zero_pads<<<(BB * 116 + 255) / 256, 256, 0, stream>>>(AD1, KDp, HD + DD, 116, BB * 116);

    u16* AE[2] = {AE0, AE1};
    for (int t = 0; t < TT; ++t) {
        gemm256<1><<<dim3(BB / 256, 2048 / 256), 512, 131072, stream>>>(
            AE[t & 1], WCE, KEp, 10, HE, CE, AE[1 - (t & 1)], be, lens, HNb, x, t);
    }

    gemm_bt<<<dim3(BB / 128, 256 / 128), 256, 0, stream>>>(HNb, WMV, MV, 256, 512);
    z_comp<<<(BB * ZZ) / 256, 256, 0, stream>>>(MV, bmu, blv, eps, out, Zbf);
    gemm_bt<<<dim3(BB / 128, 2048 / 128), 256, 0, stream>>>(Zbf, WHC, HC, 2048, 128);
    hc_init<<<(BB * HD) / 256, 256, 0, stream>>>(HC, bh0, bc0, AD0, CD);
    init_dec<<<(BB * 128) / 256, 256, 0, stream>>>(AD0, st);

    u16* AD[2] = {AD0, AD1};
    for (int t = 0; t < TT; ++t) {
        gemm256<2><<<dim3(BB / 256, 4096 / 256), 512, 131072, stream>>>(
            AD[t & 1], WCD, KDp, 18, HD, CD, AD[1 - (t & 1)], bd, nullptr, nullptr, x, t);
        outproj2<<<(BB * 64) / 256, 256, 0, stream>>>(AD[1 - (t & 1)], WOB, bout, out, t);
    }
}

// Round 6
// 4858.898 us; speedup vs baseline: 2.0167x; 1.0401x over previous
//
#include <hip/hip_runtime.h>
#include <hip/hip_bf16.h>

// ---------------- problem constants ----------------
#define BB 8192
#define TT 32
#define DD 12
#define ZZ 128
#define HE 512
#define HD 1024
#define KEp 640    // 512 + 12 -> padded to 10 x 64
#define KDp 1152   // 1024 + 12 -> padded to 18 x 64

typedef unsigned short u16;
typedef __attribute__((ext_vector_type(8))) short bf16x8;
typedef __attribute__((ext_vector_type(4))) float f32x4;

__device__ __forceinline__ u16 f2bf(float f) {
    __hip_bfloat16 h = __float2bfloat16(f);
    return *reinterpret_cast<u16*>(&h);
}
__device__ __forceinline__ float bf2f(u16 u) {
    __hip_bfloat16 h;
    *reinterpret_cast<u16*>(&h) = u;
    return __bfloat162float(h);
}
__device__ __forceinline__ float sigmf(float x) { return 1.f / (1.f + __expf(-x)); }
__device__ __forceinline__ float tanh_(float x) {
    float ax = fabsf(x);
    float e = __expf(-2.f * ax);
    float t = (1.f - e) / (1.f + e);
    return copysignf(t, x);
}

__device__ __forceinline__ void gload_lds16(const void* g, void* l) {
    __builtin_amdgcn_global_load_lds(
        (const __attribute__((address_space(1))) void*)g,
        (__attribute__((address_space(3))) void*)l,
        16, 0, 0);
}

#define BAR() asm volatile("s_barrier" ::: "memory")
#define VMCNT(n) asm volatile("s_waitcnt vmcnt(" #n ")" ::: "memory")

// ============================================================================
// 256x256 8-phase GEMM, XOR-swizzled LDS, fused LSTM epilogue.
// C[M][N] = A[M][Kp] * W[N][Kp]^T, bf16 row-major, Kp = 64*NT.
// 512 threads = 8 waves (2M x 4N); per-wave output 128x64.
// LDS: 4 regions [256 rows][64 k] bf16 (32KB each) = 128KB: (dbuf, A/B).
// Swizzle (T2, rule#21 both-sides): within each 128B row, 16B slot s at row r
// holds global k-slot s^(r&7). Stage: linear LDS dest (tid*16B + chunk*8KB),
// per-lane global src k-slot = (tid&7)^((tid>>3)&7) (row&7 == (tid>>3)&7 for
// all 4 chunks since chunk stride 64 rows). Read: slot = kslot ^ (lane&7)
// (row&7 == lane&7: row = base16*16' + (lane&15), base mult of 16).
// 16 lanes/kgroup -> 8 distinct slots -> 32 banks, 2-way = free (m136).
// Pipeline: iter n reads d0=tile 2n (p0-3), d1=tile 2n+1 (p4-7).
//   p0: stage tile 2n+1 -> d1 (8 loads);  gate vmcnt(0) end of p3.
//   p4: stage tile 2n+2 -> d0 (8 loads);  gate vmcnt(0) end of p7.
// Each gate has ~3.5 phases of MFMA+ds_read cover.
// MODE 1: encoder LSTM epilogue (+ hn capture + stage x[t+1])
// MODE 2: decoder LSTM epilogue (+ stage x[t])
// ============================================================================
#define REGION(dd, mat) (((dd)*2 + (mat)) * 16384)

#define STAGE(dd, mat, ktile) do { \
    const u16* Gp_ = (mat) ? W : A; \
    const int rb_ = (mat) ? bn : bm; \
    const int r0_ = tid >> 3; \
    const int ks_ = (ktile)*64 + (((tid & 7) ^ (r0_ & 7)) << 3); \
    u16* dst_ = &lds[REGION(dd, mat) + tid*8]; \
    const u16* s0_ = Gp_ + (size_t)(rb_ + r0_) * Kp + ks_; \
    gload_lds16(s0_,                    dst_); \
    gload_lds16(s0_ + (size_t)64  * Kp, dst_ + 4096); \
    gload_lds16(s0_ + (size_t)128 * Kp, dst_ + 8192); \
    gload_lds16(s0_ + (size_t)192 * Kp, dst_ + 12288); \
} while (0)

#define LDA4(mh, dd, kh) do { \
    const u16* bp_ = &lds[REGION(dd, 0)]; \
    const int sw_ = ((((kh)*4 + (lane >> 4)) ^ (lane & 7)) << 3); \
    _Pragma("unroll") \
    for (int i_ = 0; i_ < 4; ++i_) \
        af[i_] = *(const bf16x8*)&bp_[(wm*128 + (mh)*64 + i_*16 + (lane & 15))*64 + sw_]; \
} while (0)

#define LDB4(dd, kh) do { \
    const u16* bp_ = &lds[REGION(dd, 1)]; \
    const int sw_ = ((((kh)*4 + (lane >> 4)) ^ (lane & 7)) << 3); \
    _Pragma("unroll") \
    for (int j_ = 0; j_ < 4; ++j_) \
        bf[j_] = *(const bf16x8*)&bp_[(wn*64 + j_*16 + (lane & 15))*64 + sw_]; \
} while (0)

#define MFMA16(mh) do { \
    __builtin_amdgcn_s_setprio(1); \
    _Pragma("unroll") \
    for (int i_ = 0; i_ < 4; ++i_) \
    _Pragma("unroll") \
    for (int j_ = 0; j_ < 4; ++j_) \
        acc[(mh)*4 + i_][j_] = __builtin_amdgcn_mfma_f32_16x16x32_bf16( \
            af[i_], bf[j_], acc[(mh)*4 + i_][j_], 0, 0, 0); \
    __builtin_amdgcn_s_setprio(0); \
} while (0)

template<int MODE>
__global__ __launch_bounds__(512, 2)
void gemm256(const u16* __restrict__ A, const u16* __restrict__ W,
             int Kp, int NT, int H,
             float* __restrict__ Cst, u16* __restrict__ Aout,
             const float* __restrict__ bias, const int* __restrict__ lens,
             u16* __restrict__ HN, const float* __restrict__ X, int t)
{
    extern __shared__ u16 lds[];
    const int tid  = threadIdx.x;
    const int lane = tid & 63;
    const int wid  = tid >> 6;
    const int wm = wid >> 2, wn = wid & 3;
    const int bm = blockIdx.x * 256;
    const int bn = blockIdx.y * 256;

    f32x4 acc[8][4] = {};
    bf16x8 af[4], bf[4];

    // prologue: tile 0 -> d0
    STAGE(0, 0, 0); STAGE(0, 1, 0);
    VMCNT(0);
    BAR();

    const int NI = NT >> 1;
    for (int n = 0; n < NI; ++n) {
        const int t1 = 2*n + 1, t2 = 2*n + 2;
        const bool more = (t2 < NT);
        // p0: d0.kh0.mh0 ; stage t1 -> d1
        LDA4(0, 0, 0); LDB4(0, 0);
        STAGE(1, 0, t1); STAGE(1, 1, t1);
        BAR(); MFMA16(0); BAR();
        // p1: d0.kh0.mh1 (reuse B)
        LDA4(1, 0, 0);
        BAR(); MFMA16(1); BAR();
        // p2: d0.kh1.mh0
        LDA4(0, 0, 1); LDB4(0, 1);
        BAR(); MFMA16(0); BAR();
        // p3: d0.kh1.mh1 ; gate t1 resident
        LDA4(1, 0, 1);
        BAR(); MFMA16(1); VMCNT(0); BAR();
        // p4: d1.kh0.mh0 ; stage t2 -> d0
        LDA4(0, 1, 0); LDB4(1, 0);
        if (more) { STAGE(0, 0, t2); STAGE(0, 1, t2); }
        BAR(); MFMA16(0); BAR();
        // p5: d1.kh0.mh1
        LDA4(1, 1, 0);
        BAR(); MFMA16(1); BAR();
        // p6: d1.kh1.mh0
        LDA4(0, 1, 1); LDB4(1, 1);
        BAR(); MFMA16(0); BAR();
        // p7: d1.kh1.mh1 ; gate t2 resident
        LDA4(1, 1, 1);
        BAR(); MFMA16(1); VMCNT(0); BAR();
    }

    // ---- fused LSTM epilogue (gate-interleaved weights) ----
    // acc[a] covers rows (a*16 .. a*16+15) of the wave's 128-row strip
    // (since mh*64 + i*16 == (mh*4+i)*16).
    const int hcol = ((bn >> 6) + wn) * 16 + (lane & 15);
    const float bI = bias[hcol];
    const float bF = bias[H + hcol];
    const float bG = bias[2 * H + hcol];
    const float bO = bias[3 * H + hcol];
#pragma unroll
    for (int i = 0; i < 8; ++i) {
        const int rbase = bm + wm * 128 + i * 16 + (lane >> 4) * 4;
#pragma unroll
        for (int q = 0; q < 4; ++q) {
            const int r = rbase + q;
            float iv = sigmf(acc[i][0][q] + bI);
            float fv = sigmf(acc[i][1][q] + bF);
            float gv = tanh_(acc[i][2][q] + bG);
            float ov = sigmf(acc[i][3][q] + bO);
            float cn = fv * Cst[(size_t)r * H + hcol] + iv * gv;
            float h  = ov * tanh_(cn);
            Cst[(size_t)r * H + hcol] = cn;
            Aout[(size_t)r * Kp + hcol] = f2bf(h);
            if (MODE == 1) {
                int L = lens[r]; L = (L < 1) ? 1 : (L > TT ? TT : L);
                if (t == L - 1) HN[(size_t)r * H + hcol] = f2bf(h);
            }
        }
    }
    // stage next-step x into Aout x-columns (one block column does it)
    const int tx = (MODE == 1) ? t + 1 : t;
    if (bn == 0 && tx < TT) {
        for (int ii = tid; ii < 256 * DD; ii += 512) {
            const int rr = ii / DD, d = ii - rr * DD;
            const int r = bm + rr;
            Aout[(size_t)r * Kp + H + d] = f2bf(X[((size_t)r * TT + tx) * DD + d]);
        }
    }
}

// ---------------- plain 128x128 GEMM (small matmuls): C = A * W^T ----------
__global__ __launch_bounds__(256, 2)
void gemm_bt(const u16* __restrict__ A, const u16* __restrict__ W,
             float* __restrict__ C, int N, int K)
{
    __shared__ u16 As[128 * 64];
    __shared__ u16 Ws[128 * 64];
    const int tid  = threadIdx.x;
    const int lane = tid & 63;
    const int wave = tid >> 6;
    const int wm = wave >> 1, wn = wave & 1;
    const int bm = blockIdx.x * 128;
    const int bn = blockIdx.y * 128;

    f32x4 acc[4][4] = {};
    const int lrow = lane >> 3;
    const int lcol = (lane & 7) * 8;

    for (int kt = 0; kt < K; kt += 64) {
#pragma unroll
        for (int c2 = 0; c2 < 4; ++c2) {
            const int chunk = wave * 4 + c2;
            const int row = chunk * 8 + lrow;
            gload_lds16(A + (size_t)(bm + row) * K + kt + lcol, &As[chunk * 512]);
            gload_lds16(W + (size_t)(bn + row) * K + kt + lcol, &Ws[chunk * 512]);
        }
        __syncthreads();
#pragma unroll
        for (int ks = 0; ks < 2; ++ks) {
            bf16x8 af[4], wf[4];
            const int ko = ks * 32 + (lane >> 4) * 8;
            const int rA = wm * 64 + (lane & 15);
            const int rW = wn * 64 + (lane & 15);
#pragma unroll
            for (int i = 0; i < 4; ++i)
                af[i] = *(const bf16x8*)&As[(rA + i * 16) * 64 + ko];
#pragma unroll
            for (int i = 0; i < 4; ++i)
                wf[i] = *(const bf16x8*)&Ws[(rW + i * 16) * 64 + ko];
#pragma unroll
            for (int i = 0; i < 4; ++i)
#pragma unroll
                for (int j = 0; j < 4; ++j)
                    acc[i][j] = __builtin_amdgcn_mfma_f32_16x16x32_bf16(
                        af[i], wf[j], acc[i][j], 0, 0, 0);
        }
        __syncthreads();
    }
    const int r0 = bm + wm * 64 + (lane >> 4) * 4;
    const int c0 = bn + wn * 64 + (lane & 15);
#pragma unroll
    for (int i = 0; i < 4; ++i)
#pragma unroll
        for (int j = 0; j < 4; ++j) {
            float* Cp = C + (size_t)(r0 + i * 16) * N + c0 + j * 16;
#pragma unroll
            for (int q = 0; q < 4; ++q)
                Cp[(size_t)q * N] = acc[i][j][q];
        }
}

// ---------------- gate-interleaved weight concat (padded K) ----------------
// n' = 64*(j>>4) + 16*gate + (j&15); row = [Whh[gate*H+j] | Wih[gate*H+j] | 0]
__global__ void prep_wg(const float* __restrict__ Whh, const float* __restrict__ Wih,
                        u16* __restrict__ dst, int H, int Kc, int total)
{
    int idx = blockIdx.x * 256 + threadIdx.x;
    if (idx >= total) return;
    int np = idx / Kc, k = idx - np * Kc;
    int jblk = np >> 6, rem = np & 63;
    int gate = rem >> 4, jl = rem & 15;
    int j = jblk * 16 + jl;
    int srow = gate * H + j;
    float v = 0.f;
    if (k < H) v = Whh[(size_t)srow * H + k];
    else if (k < H + DD) v = Wih[srow * DD + (k - H)];
    dst[idx] = f2bf(v);
}

// ---------------- plain stacked concat (bf16): [W0; W1] ----------------
__global__ void prep_cat(const float* __restrict__ W0, const float* __restrict__ W1,
                         u16* __restrict__ dst, int rows0, int K, int total)
{
    int idx = blockIdx.x * 256 + threadIdx.x;
    if (idx >= total) return;
    int n = idx / K, k = idx - n * K;
    float v = (n < rows0) ? W0[(size_t)n * K + k] : W1[(size_t)(n - rows0) * K + k];
    dst[idx] = f2bf(v);
}

__global__ void prep_bf(const float* __restrict__ src, u16* __restrict__ dst, int total)
{
    int idx = blockIdx.x * 256 + threadIdx.x;
    if (idx < total) dst[idx] = f2bf(src[idx]);
}

// ---------------- encoder init: h=0, x col = x[:,0,:], pad=0; c=0 ----------
__global__ void init_enc(u16* __restrict__ A, float* __restrict__ c, const float* __restrict__ x)
{
    int idx = blockIdx.x * 256 + threadIdx.x;   // BB*KEp
    int b = idx / KEp, j = idx - b * KEp;
    u16 v = 0;
    if (j >= HE && j < HE + DD) v = f2bf(x[(size_t)b * (TT * DD) + (j - HE)]);
    A[idx] = v;
    if (j < HE) c[(size_t)b * HE + j] = 0.f;
}

// ---------------- zero pad columns [lo, lo+n) of A[BB][ldK] ----------------
__global__ void zero_pads(u16* __restrict__ A, int ldK, int lo, int n, int total)
{
    int idx = blockIdx.x * 256 + threadIdx.x;
    if (idx >= total) return;
    int b = idx / n, j = idx - b * n;
    A[(size_t)b * ldK + lo + j] = 0;
}

// ---------------- z from MV = [mu | lv] fp32 ----------------
__global__ void z_comp(const float* __restrict__ MV, const float* __restrict__ bmu,
                       const float* __restrict__ blv, const float* __restrict__ eps,
                       float* __restrict__ out, u16* __restrict__ Zbf)
{
    int idx = blockIdx.x * 256 + threadIdx.x;   // BB*ZZ
    int b = idx >> 7, zc = idx & (ZZ - 1);
    float mu = MV[(size_t)b * 256 + zc] + bmu[zc];
    float lv = MV[(size_t)b * 256 + ZZ + zc] + blv[zc];
    float z = mu + eps[idx] * __expf(0.5f * lv);
    const size_t XR = (size_t)BB * TT * DD;
    out[XR + idx] = mu;
    out[XR + (size_t)BB * ZZ + idx] = lv;
    out[XR + 2 * (size_t)BB * ZZ + idx] = z;
    Zbf[idx] = f2bf(z);
}

// ---------------- decoder state init from HC = [h0pre | c0pre] -------------
__global__ void hc_init(const float* __restrict__ HC, const float* __restrict__ bh0,
                        const float* __restrict__ bc0, u16* __restrict__ A,
                        float* __restrict__ c)
{
    int idx = blockIdx.x * 256 + threadIdx.x;   // BB*HD
    int b = idx >> 10, j = idx & (HD - 1);
    float h0 = tanh_(HC[(size_t)b * 2048 + j] + bh0[j]);
    float c0 = tanh_(HC[(size_t)b * 2048 + HD + j] + bc0[j]);
    A[(size_t)b * KDp + j] = f2bf(h0);
    c[idx] = c0;
}

// ---------------- decoder x-col init: start token + zero pad to KDp --------
__global__ void init_dec(u16* __restrict__ A, const float* __restrict__ st)
{
    int idx = blockIdx.x * 256 + threadIdx.x;   // BB*128
    int b = idx >> 7, j = idx & 127;
    A[(size_t)b * KDp + HD + j] = (j < DD) ? f2bf(st[j]) : (u16)0;
}

// ---------------- output projection: wave per row, butterfly reduce --------
__global__ void outproj2(const u16* __restrict__ A, const u16* __restrict__ Wb,
                         const float* __restrict__ bout, float* __restrict__ xr, int t)
{
    int gid = blockIdx.x * 256 + threadIdx.x;
    int b = gid >> 6;
    int lane = threadIdx.x & 63;
    const u16* h = A + (size_t)b * KDp;
    const int k0 = lane * 16;
    bf16x8 h0 = *(const bf16x8*)&h[k0];
    bf16x8 h1 = *(const bf16x8*)&h[k0 + 8];
    float hv[16];
#pragma unroll
    for (int k = 0; k < 8; ++k) { hv[k] = bf2f((u16)h0[k]); hv[k + 8] = bf2f((u16)h1[k]); }
    float acc[DD];
#pragma unroll
    for (int d = 0; d < DD; ++d) {
        const u16* w = Wb + d * HD + k0;
        bf16x8 w0 = *(const bf16x8*)&w[0];
        bf16x8 w1 = *(const bf16x8*)&w[8];
        float a = 0.f;
#pragma unroll
        for (int k = 0; k < 8; ++k)
            a += hv[k] * bf2f((u16)w0[k]) + hv[k + 8] * bf2f((u16)w1[k]);
        acc[d] = a;
    }
#pragma unroll
    for (int off = 32; off > 0; off >>= 1)
#pragma unroll
        for (int d = 0; d < DD; ++d)
            acc[d] += __shfl_xor(acc[d], off);
    if (lane < DD)
        xr[((size_t)b * TT + t) * DD + lane] = acc[lane] + bout[lane];
}

// ---------------- launch ----------------
extern "C" void kernel_launch(void* const* d_in, const int* in_sizes, int n_in,
                              void* d_out, int out_size, void* d_ws, size_t ws_size,
                              hipStream_t stream)
{
    const float* x    = (const float*)d_in[0];
    const int*   lens = (const int*)d_in[1];
    const float* eps  = (const float*)d_in[2];
    const float* Wihe = (const float*)d_in[3];
    const float* Whhe = (const float*)d_in[4];
    const float* be   = (const float*)d_in[5];
    const float* Wmu  = (const float*)d_in[6];
    const float* bmu  = (const float*)d_in[7];
    const float* Wlv  = (const float*)d_in[8];
    const float* blv  = (const float*)d_in[9];
    const float* Wh0  = (const float*)d_in[10];
    const float* bh0  = (const float*)d_in[11];
    const float* Wc0  = (const float*)d_in[12];
    const float* bc0  = (const float*)d_in[13];
    const float* st   = (const float*)d_in[14];
    const float* Wihd = (const float*)d_in[15];
    const float* Whhd = (const float*)d_in[16];
    const float* bd   = (const float*)d_in[17];
    const float* Wout = (const float*)d_in[18];
    const float* bout = (const float*)d_in[19];
    float* out = (float*)d_out;

    char* ws = (char*)d_ws;
    size_t o = 0;
    u16*   WCE = (u16*)(ws + o); o += (size_t)2048 * KEp * 2;  //  2,621,440
    u16*   WCD = (u16*)(ws + o); o += (size_t)4096 * KDp * 2;  //  9,437,184
    u16*   WMV = (u16*)(ws + o); o += (size_t)256 * 512 * 2;   //    262,144
    u16*   WHC = (u16*)(ws + o); o += (size_t)2048 * 128 * 2;  //    524,288
    u16*   WOB = (u16*)(ws + o); o += 32768;
    u16*   AE0 = (u16*)(ws + o); o += (size_t)BB * KEp * 2;    // 10,485,760
    u16*   AE1 = (u16*)(ws + o); o += (size_t)BB * KEp * 2;
    u16*   AD0 = (u16*)(ws + o); o += (size_t)BB * KDp * 2;    // 18,874,368
    u16*   AD1 = (u16*)(ws + o); o += (size_t)BB * KDp * 2;
    float* CE  = (float*)(ws + o); o += (size_t)BB * HE * 4;   // 16,777,216
    float* CD  = (float*)(ws + o); o += (size_t)BB * HD * 4;   // 33,554,432
    u16*   HNb = (u16*)(ws + o); o += (size_t)BB * HE * 2;     //  8,388,608
    float* MV  = (float*)(ws + o); o += (size_t)BB * 256 * 4;  //  8,388,608
    u16*   Zbf = (u16*)(ws + o); o += (size_t)BB * ZZ * 2;     //  2,097,152
    float* HC  = (float*)(ws + o); o += (size_t)BB * 2048 * 4; // 67,108,864
    // total ~216 MB

    hipFuncSetAttribute((const void*)gemm256<1>,
                        hipFuncAttributeMaxDynamicSharedMemorySize, 131072);
    hipFuncSetAttribute((const void*)gemm256<2>,
                        hipFuncAttributeMaxDynamicSharedMemorySize, 131072);

    prep_wg<<<(2048 * KEp + 255) / 256, 256, 0, stream>>>(Whhe, Wihe, WCE, HE, KEp, 2048 * KEp);
    prep_wg<<<(4096 * KDp + 255) / 256, 256, 0, stream>>>(Whhd, Wihd, WCD, HD, KDp, 4096 * KDp);
    prep_cat<<<(256 * 512 + 255) / 256, 256, 0, stream>>>(Wmu, Wlv, WMV, ZZ, HE, 256 * 512);
    prep_cat<<<(2048 * 128 + 255) / 256, 256, 0, stream>>>(Wh0, Wc0, WHC, HD, ZZ, 2048 * 128);
    prep_bf<<<(12 * HD + 255) / 256, 256, 0, stream>>>(Wout, WOB, 12 * HD);
    init_enc<<<(BB * KEp) / 256, 256, 0, stream>>>(AE0, CE, x);
    zero_pads<<<(BB * 116 + 255) / 256, 256, 0, stream>>>(AE1, KEp, HE + DD, 116, BB * 116);
    zero_pads<<<(BB * 116 + 255) / 256, 256, 0, stream>>>(AD1, KDp, HD + DD, 116, BB * 116);

    u16* AE[2] = {AE0, AE1};
    for (int t = 0; t < TT; ++t) {
        gemm256<1><<<dim3(BB / 256, 2048 / 256), 512, 131072, stream>>>(
            AE[t & 1], WCE, KEp, 10, HE, CE, AE[1 - (t & 1)], be, lens, HNb, x, t);
    }

    gemm_bt<<<dim3(BB / 128, 256 / 128), 256, 0, stream>>>(HNb, WMV, MV, 256, 512);
    z_comp<<<(BB * ZZ) / 256, 256, 0, stream>>>(MV, bmu, blv, eps, out, Zbf);
    gemm_bt<<<dim3(BB / 128, 2048 / 128), 256, 0, stream>>>(Zbf, WHC, HC, 2048, 128);
    hc_init<<<(BB * HD) / 256, 256, 0, stream>>>(HC, bh0, bc0, AD0, CD);
    init_dec<<<(BB * 128) / 256, 256, 0, stream>>>(AD0, st);

    u16* AD[2] = {AD0, AD1};
    for (int t = 0; t < TT; ++t) {
        gemm256<2><<<dim3(BB / 256, 4096 / 256), 512, 131072, stream>>>(
            AD[t & 1], WCD, KDp, 18, HD, CD, AD[1 - (t & 1)], bd, nullptr, nullptr, x, t);
        outproj2<<<(BB * 64) / 256, 256, 0, stream>>>(AD[1 - (t & 1)], WOB, bout, out, t);
    }
}